// Round 6
// baseline (173.740 us; speedup 1.0000x reference)
//
#include <hip/hip_runtime.h>

// Multi-kernel EM split. Shapes (fp32): x(8,14,14,32,16) a(8,14,14,32)
// W(288,32,16) beta_u(32) beta_a(32); out: p_out 147456 + a_out 9216.
// Round 2 (monolith, 288 blocks) = 96 us dispatch, VALUBusy 23%, Occ 12.8%:
// grid-starved + serial softmax chains. Rounds 3-5: every attempt to raise the
// 64-VGPR heuristic cap (launch_bounds 2nd arg, waves_per_eu) was ignored ->
// 39 MB spill. Fix is structural: split each EM iteration into its own launch,
// split n across 4 blocks/position (grid 1152), combine via fp32 atomics in ws.
// Inner loop is EXACTLY round 2's proven 80-VGPR shape (no pairing).

#define NPOS 288
#define ASTR 33              // per-(pos,c) accumulator stride: 16 m + 16 v + rs
#define ACC_FLOATS ((size_t)NPOS * 32 * ASTR)

// ---------------- stats: one EM iteration's fused E+M pass ----------------
// grid 1152 = pos*4 + split; block 512 = 16 n-slices x 32 c; 72 n per block.
template <bool FIRST>
__global__ __launch_bounds__(512) void stats_kernel(
    const float* __restrict__ xg,
    const float* __restrict__ ag,
    const float* __restrict__ wg,
    const float* __restrict__ tabs,   // [pos][c][33]: A[16] B[16] Kc
    float* __restrict__ acc)          // [pos][c][33]: m[16] v[16] rs
{
    __shared__ __align__(16) float pose_s[72 * 16];
    __shared__ float a_s[72];
    __shared__ __align__(16) float scratch[8448];  // 8 waves x 32 c x 33
    __shared__ float rsum_part[256];               // 8 waves x 32 c

    const int tid   = threadIdx.x;
    const int blk   = blockIdx.x;
    const int pos   = blk >> 2;
    const int nbase = (blk & 3) * 72;
    const int bb  = pos / 36;
    const int rem = pos % 36;
    const int yy  = rem / 6;
    const int xx  = rem % 6;

    // ---- stage this block's 72 pose rows (+ a_in) into LDS ----
    for (int i = tid; i < 72 * 16; i += 512) {
        const int nl = i >> 4, off = i & 15;
        const int n  = nbase + nl;
        const int wi = n >> 5, bi = n & 31;
        const int kh = wi / 3, kw = wi % 3;
        pose_s[i] = xg[((size_t)(((bb * 14) + (2 * yy + kh)) * 14 + (2 * xx + kw)) * 32 + bi) * 16 + off];
    }
    if (tid < 72) {
        const int n  = nbase + tid;
        const int wi = n >> 5, bi = n & 31;
        const int kh = wi / 3, kw = wi % 3;
        a_s[tid] = ag[(size_t)(((bb * 14) + (2 * yy + kh)) * 14 + (2 * xx + kw)) * 32 + bi];
    }
    __syncthreads();

    const int c    = tid & 31;   // capsule-out index
    const int s    = tid >> 5;   // n-slice 0..15
    const int lane = tid & 63;
    const int wv   = tid >> 6;   // wave 0..7
    const float4* wp = (const float4*)wg;

    // hoisted per-c routing state: dist = sum_p v*(v*A - B), consts folded in Kc
    float A_c[16], B_c[16], Kc = 0.f;
    if (!FIRST) {
        const float* tb = tabs + ((size_t)pos * 32 + c) * ASTR;
        #pragma unroll
        for (int p = 0; p < 16; ++p) { A_c[p] = tb[p]; B_c[p] = tb[16 + p]; }
        Kc = tb[32];
    }
    float macc[16], vacc[16], rs = 0.f;
    #pragma unroll
    for (int p = 0; p < 16; ++p) { macc[p] = 0.f; vacc[p] = 0.f; }

    // ---- fused E+M over this thread's n values (nl = 16k + s < 72) ----
    #pragma unroll 1
    for (int k = 0; k < 5; ++k) {
        const int nl = k * 16 + s;
        if (nl < 72) {
            const int n = nbase + nl;
            const float4* pp = (const float4*)&pose_s[nl << 4];
            float pf[16];
            float4 q;
            q = pp[0]; pf[0]=q.x;  pf[1]=q.y;  pf[2]=q.z;  pf[3]=q.w;
            q = pp[1]; pf[4]=q.x;  pf[5]=q.y;  pf[6]=q.z;  pf[7]=q.w;
            q = pp[2]; pf[8]=q.x;  pf[9]=q.y;  pf[10]=q.z; pf[11]=q.w;
            q = pp[3]; pf[12]=q.x; pf[13]=q.y; pf[14]=q.z; pf[15]=q.w;
            const int wbase = (n * 32 + c) * 4;
            float wf[16];
            float4 w0 = wp[wbase + 0]; wf[0]=w0.x;  wf[1]=w0.y;  wf[2]=w0.z;  wf[3]=w0.w;
            float4 w1 = wp[wbase + 1]; wf[4]=w1.x;  wf[5]=w1.y;  wf[6]=w1.z;  wf[7]=w1.w;
            float4 w2 = wp[wbase + 2]; wf[8]=w2.x;  wf[9]=w2.y;  wf[10]=w2.z; wf[11]=w2.w;
            float4 w3 = wp[wbase + 3]; wf[12]=w3.x; wf[13]=w3.y; wf[14]=w3.z; wf[15]=w3.w;
            // v = pose(4x4) @ W(4x4), flattened p = i*4+l
            float v[16];
            #pragma unroll
            for (int i = 0; i < 4; ++i)
                #pragma unroll
                for (int l = 0; l < 4; ++l)
                    v[i*4+l] = pf[i*4+0] * wf[0*4+l] + pf[i*4+1] * wf[1*4+l]
                             + pf[i*4+2] * wf[2*4+l] + pf[i*4+3] * wf[3*4+l];
            float r;
            if (FIRST) {
                r = a_s[nl] * 0.03125f;   // (1/C)*a_in — c-uniform, no softmax
            } else {
                float t = 0.f;
                #pragma unroll
                for (int p = 0; p < 16; ++p)
                    t = fmaf(fmaf(v[p], A_c[p], -B_c[p]), v[p], t);
                float lnap = -t - Kc;
                // softmax over the 32 c-lanes (uniform n per group — no divergence)
                float m = lnap;
                #pragma unroll
                for (int msk = 16; msk >= 1; msk >>= 1) m = fmaxf(m, __shfl_xor(m, msk));
                float e = __expf(lnap - m);
                float sum = e;
                #pragma unroll
                for (int msk = 16; msk >= 1; msk >>= 1) sum += __shfl_xor(sum, msk);
                r = e / sum;
            }
            rs += r;
            #pragma unroll
            for (int p = 0; p < 16; ++p) {
                float rv = r * v[p];
                macc[p] = fmaf(r, v[p], macc[p]);
                vacc[p] = fmaf(rv, v[p], vacc[p]);
            }
        }
    }

    // ---- in-block reduction: shfl pair, then LDS tree over 8 waves ----
    #pragma unroll
    for (int p = 0; p < 16; ++p) {
        macc[p] += __shfl_xor(macc[p], 32);
        vacc[p] += __shfl_xor(vacc[p], 32);
    }
    rs += __shfl_xor(rs, 32);
    if (lane < 32) {  // c = lane
        const int base = (wv * 32 + lane) * 33;  // +33 stride: conflict-free
        #pragma unroll
        for (int p = 0; p < 16; ++p) {
            scratch[base + p]      = macc[p];
            scratch[base + 16 + p] = vacc[p];
        }
        rsum_part[wv * 32 + lane] = rs;
    }
    __syncthreads();

    // ---- (fc, fp) threads sum 8 wave-slots, atomicAdd into global acc ----
    const int fc = tid >> 4, fp = tid & 15;
    float ms = 0.f, vs = 0.f, rsc = 0.f;
    #pragma unroll
    for (int w = 0; w < 8; ++w) {
        ms  += scratch[(w * 32 + fc) * 33 + fp];
        vs  += scratch[(w * 32 + fc) * 33 + 16 + fp];
        rsc += rsum_part[w * 32 + fc];
    }
    float* ac = acc + ((size_t)pos * 32 + fc) * ASTR;
    atomicAdd(&ac[fp],      ms);
    atomicAdd(&ac[16 + fp], vs);
    if (fp == 0) atomicAdd(&ac[32], rsc);
}

// ---------------- finalize: stats -> routing tabs (or outputs) ----------------
// grid 288 x 512; thread = (fc = tid>>4, fp = tid&15). Also re-zeroes acc.
template <bool LAST>
__global__ __launch_bounds__(512) void fin_kernel(
    float* __restrict__ acc,
    float* __restrict__ tabs,
    const float* __restrict__ bu,
    const float* __restrict__ ba,
    float* __restrict__ outp)
{
    const int tid = threadIdx.x, pos = blockIdx.x;
    const int fc = tid >> 4, fp = tid & 15;
    float* ac = acc + ((size_t)pos * 32 + fc) * ASTR;
    const float ms  = ac[fp];
    const float vs  = ac[16 + fp];
    const float rsc = ac[32];

    const float inv = 1.f / (rsc + 1e-6f);
    const float S   = rsc * inv;
    const float mu  = ms * inv;
    const float sig = vs * inv - mu * mu * (2.f - S) + 1e-6f;
    const float ia  = 0.5f / sig;
    const float lg  = __logf(sig);
    const float cs  = mu * mu * ia;
    float lgs = lg, ccs = cs;   // reduce over the 16 p-lanes sharing fc
    #pragma unroll
    for (int msk = 8; msk >= 1; msk >>= 1) {
        lgs += __shfl_xor(lgs, msk);
        ccs += __shfl_xor(ccs, msk);
    }
    const float cost = rsc * (16.f * bu[fc] + 0.5f * lgs);
    const float ao   = 1.f / (1.f + __expf(-0.001f * (ba[fc] - cost)));

    // re-zero acc for the next stats pass (ws is re-poisoned 0xAA each call)
    ac[fp] = 0.f; ac[16 + fp] = 0.f;
    if (fp == 0) ac[32] = 0.f;

    if (LAST) {
        outp[(size_t)pos * 512 + tid] = mu;                    // p_out
        if (fp == 0) outp[147456 + (size_t)pos * 32 + fc] = ao;  // a_out
    } else {
        float* tb = tabs + ((size_t)pos * 32 + fc) * ASTR;
        tb[fp]      = ia;             // A = 0.5/sigma
        tb[16 + fp] = 2.f * mu * ia;  // B = mu/sigma
        if (fp == 0) tb[32] = 0.5f * lgs - __logf(ao) + ccs;   // Kc
    }
}

extern "C" void kernel_launch(void* const* d_in, const int* in_sizes, int n_in,
                              void* d_out, int out_size, void* d_ws, size_t ws_size,
                              hipStream_t stream) {
    (void)in_sizes; (void)n_in; (void)out_size; (void)ws_size;
    const float* x  = (const float*)d_in[0];
    const float* a  = (const float*)d_in[1];
    const float* w  = (const float*)d_in[2];
    const float* bu = (const float*)d_in[3];
    const float* ba = (const float*)d_in[4];
    float* out  = (float*)d_out;
    float* acc  = (float*)d_ws;            // 288*32*33 floats = 1.22 MB
    float* tabs = acc + ACC_FLOATS;        // same size; total ws use 2.43 MB

    hipMemsetAsync(acc, 0, ACC_FLOATS * sizeof(float), stream);

    stats_kernel<true ><<<dim3(NPOS * 4), dim3(512), 0, stream>>>(x, a, w, tabs, acc);
    fin_kernel  <false><<<dim3(NPOS),     dim3(512), 0, stream>>>(acc, tabs, bu, ba, out);
    stats_kernel<false><<<dim3(NPOS * 4), dim3(512), 0, stream>>>(x, a, w, tabs, acc);
    fin_kernel  <false><<<dim3(NPOS),     dim3(512), 0, stream>>>(acc, tabs, bu, ba, out);
    stats_kernel<false><<<dim3(NPOS * 4), dim3(512), 0, stream>>>(x, a, w, tabs, acc);
    fin_kernel  <true ><<<dim3(NPOS),     dim3(512), 0, stream>>>(acc, tabs, bu, ba, out);
}